// Round 2
// baseline (174.641 us; speedup 1.0000x reference)
//
#include <hip/hip_runtime.h>

// ---------------------------------------------------------------------------
// UniversalBlockEncoder: algebraically folded attention pooling.
//
//   u_i = silu(W1 x_i + b1)                 (the only per-point nonlinearity)
//   s_h(i) = g_h . u_i + d_h    with g_h = W2^T (scale Wk_h^T q_h)
//   p = exp(s)  (scores O(3), f32-safe without max-subtraction)
//   T_h = sum_i p_h(i) u_i ,  l_h = sum_i p_h(i)
//   out = Wo ( Wv ( W2 (T/l) + b2 ) + bv ) + bo
//
// R9: R8 with finish_kernel FUSED into main via a device-scope done-counter:
//     the last block to finish its atomics runs the finish math inline
//     (agent-scoped atomic loads of the accumulator slots -> safe vs
//     cross-XCD L2 staleness). Removes one dispatch + its graph gap.
//     Phase 1 (packed f32), phase 2 (MFMA), epilogue: unchanged from R8.
// ---------------------------------------------------------------------------

#define LOG2E 1.44269504088896340736f
#define NLN2  (-0.69314718055994530942f)

#if __has_builtin(__builtin_amdgcn_exp2f)
#define EXP2(x) __builtin_amdgcn_exp2f(x)
#else
#define EXP2(x) exp2f(x)
#endif
#if __has_builtin(__builtin_amdgcn_rcpf)
#define RCP(x) __builtin_amdgcn_rcpf(x)
#else
#define RCP(x) (1.0f / (x))
#endif

// LDS-only ordering within a wave (each wave touches only its own region;
// wave lockstep => lgkmcnt(0) is a sufficient producer-consumer barrier).
#define LDS_WAIT() asm volatile("s_waitcnt lgkmcnt(0)" ::: "memory")

typedef __attribute__((ext_vector_type(8))) __bf16 bf16x8;
typedef __attribute__((ext_vector_type(4))) float  f32x4;
typedef __attribute__((ext_vector_type(2))) float  f32x2;

__device__ __forceinline__ f32x2 fma2(f32x2 a, f32x2 b, f32x2 c) {
#if __has_builtin(__builtin_elementwise_fma)
    return __builtin_elementwise_fma(a, b, c);
#else
    return (f32x2){fmaf(a.x, b.x, c.x), fmaf(a.y, b.y, c.y)};
#endif
}

__device__ __forceinline__ float agent_load(const float* p) {
    return __hip_atomic_load(p, __ATOMIC_RELAXED, __HIP_MEMORY_SCOPE_AGENT);
}

// workspace float offsets
#define WS_PK   0      // 32 pairs x 16 floats (pair-SoA constants)
#define WS_D    512    // 4           : log2e * d_h
#define WS_ACC  768    // NSLOT x SLOTSTRIDE: [0..3]=l_h, [4+h*64+j]=T'_h[j]
#define NSLOT      16
#define SLOTSTRIDE 272
#define WS_CNT  (WS_ACC + NSLOT * SLOTSTRIDE)   // done-counter (uint), zeroed by setup

#define NPTS       (1024 * 1024)
#define K1_BLOCKS  2048
#define K1_THREADS 128
#define WAVES_TOTAL (K1_BLOCKS * 2)                   // 4096
#define GROUPS_PER_WAVE ((NPTS / 64) / WAVES_TOTAL)   // 4

// per-wave LDS region (shorts): p[4 x 72] + u[64 x 72]
#define PW_SHORTS  288
#define UW_SHORTS  (64 * 72)
#define WAVE_SHORTS (PW_SHORTS + UW_SHORTS)  // 4896 shorts (9792 B)

__device__ __forceinline__ unsigned short to_bf16(float x) {
    return (unsigned short)((__float_as_uint(x) + 0x8000u) >> 16);
}

// ---------------------------------------------------------------------------
// Setup: 64 blocks x 64 threads. Every block redundantly computes q and a
// (coalesced); block j computes g[j][h] lane-per-d + shuffle reduce. All
// blocks cooperatively zero the accumulator slots + done-counter.
__global__ void setup_kernel(const float* __restrict__ W1, const float* __restrict__ b1,
                             const float* __restrict__ W2, const float* __restrict__ b2,
                             const float* __restrict__ query,
                             const float* __restrict__ ipw, const float* __restrict__ ipb,
                             float* __restrict__ ws)
{
    __shared__ float qv[64], qs[64], as4[4][64];
    const int t = threadIdx.x;
    const int b = blockIdx.x;     // = output j

    for (int i = b * 64 + t; i < NSLOT * SLOTSTRIDE + 64; i += 64 * 64)
        ws[WS_ACC + i] = 0.0f;    // covers slots AND the done-counter

    qv[t] = query[t];
    __syncthreads();

    {
        float a = ipb[t];
        #pragma unroll
        for (int k = 0; k < 64; ++k) a = fmaf(ipw[t * 64 + k], qv[k], a);
        qs[t] = a;
    }
    __syncthreads();

    #pragma unroll
    for (int h = 0; h < 4; ++h) {
        float a = 0.0f;
        #pragma unroll
        for (int m = 0; m < 16; ++m)
            a = fmaf(ipw[(64 + h * 16 + m) * 64 + t], qs[h * 16 + m], a);
        as4[h][t] = 0.25f * a;
    }
    __syncthreads();

    const float w2 = W2[t * 64 + b];
    float g[4];
    #pragma unroll
    for (int h = 0; h < 4; ++h) {
        float v = as4[h][t] * w2;
        for (int m = 1; m < 64; m <<= 1) v += __shfl_xor(v, m);
        g[h] = v;
    }
    if (t == 0) {
        const int base = 16 * (b >> 1);
        const int sub  = b & 1;
        ws[WS_PK + base + 0  + sub] = -LOG2E * W1[2 * b];      // cx
        ws[WS_PK + base + 2  + sub] = -LOG2E * W1[2 * b + 1];  // cy
        ws[WS_PK + base + 4  + sub] = -LOG2E * b1[b];          // cz
        ws[WS_PK + base + 6  + sub] = 0.0f;                    // pad
        ws[WS_PK + base + 8  + sub] = -g[0];                   // -g: LOG2E*NLN2 fold
        ws[WS_PK + base + 10 + sub] = -g[1];
        ws[WS_PK + base + 12 + sub] = -g[2];
        ws[WS_PK + base + 14 + sub] = -g[3];
    }
    if (b == 0 && t < 4) {
        float d = 0.0f;
        #pragma unroll
        for (int c = 0; c < 64; ++c) d += as4[t][c] * b2[c];
        float qb = 0.0f;
        #pragma unroll
        for (int m = 0; m < 16; ++m) qb += qs[t * 16 + m] * ipb[64 + t * 16 + m];
        ws[WS_D + t] = LOG2E * (d + 0.25f * qb);
    }
}

// ---------------------------------------------------------------------------
// Main: 2 independent waves/block (own LDS regions; pure-lgkm waits).
// Phase 1 (lane = point): hidden units in PAIRS via packed f32 math.
// Phase 2: 8x mfma_f32_16x16x32_bf16 per group.
// Epilogue: transpose D via LDS -> coalesced atomics -> done-counter;
// the LAST block runs the finish math inline (128 threads).
__global__ __launch_bounds__(K1_THREADS, 4) void main_kernel(
        const float* __restrict__ rr, const float* __restrict__ ri,
        const float4* __restrict__ pk4,
        const float* __restrict__ dvec, float* __restrict__ accb,
        unsigned int* __restrict__ cnt,
        const float* __restrict__ W2, const float* __restrict__ b2,
        const float* __restrict__ ipw, const float* __restrict__ ipb,
        const float* __restrict__ opw, const float* __restrict__ opb,
        float* __restrict__ out)
{
    __shared__ __align__(16) unsigned short lds[2][WAVE_SHORTS];
    __shared__ unsigned int lastFlag;

    const int t    = threadIdx.x;
    const int lane = t & 63;
    const int w    = t >> 6;
    const int m    = lane & 15;
    const int q    = lane >> 4;

    unsigned short* pw = lds[w];               // p: [h][pt], stride 72
    unsigned short* uw = lds[w] + PW_SHORTS;   // u: [j][pt], stride 72

    const float d0 = dvec[0], d1 = dvec[1], d2 = dvec[2], d3 = dvec[3];

    const int gwave = blockIdx.x * 2 + w;
    float l0 = 0, l1 = 0, l2 = 0, l3 = 0;
    f32x4 acc[4];
    #pragma unroll
    for (int i = 0; i < 4; ++i) acc[i] = (f32x4){0.f, 0.f, 0.f, 0.f};

    // hoist ALL global loads to kernel entry
    float rv[GROUPS_PER_WAVE], iv[GROUPS_PER_WAVE];
    #pragma unroll
    for (int it = 0; it < GROUPS_PER_WAVE; ++it) {
        const int idx = (gwave + it * WAVES_TOTAL) * 64 + lane;
        rv[it] = rr[idx];
        iv[it] = ri[idx];
    }

    for (int it = 0; it < GROUPS_PER_WAVE; ++it) {
        const f32x2 r2 = {rv[it], rv[it]};
        const f32x2 i2 = {iv[it], iv[it]};

        // packed score partials; halves summed after the loop
        f32x2 s0v = {d0, 0.f}, s1v = {d1, 0.f}, s2v = {d2, 0.f}, s3v = {d3, 0.f};

        #pragma unroll 8
        for (int jp = 0; jp < 32; ++jp) {
            const float4 A  = pk4[4 * jp + 0];   // {cx0,cx1,cy0,cy1} wave-uniform
            const float4 B  = pk4[4 * jp + 1];   // {cz0,cz1, 0, 0 }
            const float4 C  = pk4[4 * jp + 2];   // {g00,g01,g10,g11}
            const float4 Dv = pk4[4 * jp + 3];   // {g20,g21,g30,g31}

            const f32x2 cx = {A.x, A.y};
            const f32x2 cy = {A.z, A.w};
            const f32x2 cz = {B.x, B.y};

            const f32x2 zn = fma2(cx, r2, fma2(cy, i2, cz));     // -log2e * z
            const f32x2 e  = {EXP2(zn.x), EXP2(zn.y)};           // exp(-z)
            const f32x2 op = e + (f32x2){1.f, 1.f};
            const f32x2 rc = {RCP(op.x), RCP(op.y)};             // sigmoid(z)
            const f32x2 ub = zn * rc;            // = u / NLN2  (fold)

            s0v = fma2((f32x2){C.x,  C.y},  ub, s0v);
            s1v = fma2((f32x2){C.z,  C.w},  ub, s1v);
            s2v = fma2((f32x2){Dv.x, Dv.y}, ub, s2v);
            s3v = fma2((f32x2){Dv.z, Dv.w}, ub, s3v);

            uw[(2 * jp)     * 72 + lane] = to_bf16(ub.x);
            uw[(2 * jp + 1) * 72 + lane] = to_bf16(ub.y);
        }
        const float p0 = EXP2(s0v.x + s0v.y), p1 = EXP2(s1v.x + s1v.y);
        const float p2 = EXP2(s2v.x + s2v.y), p3 = EXP2(s3v.x + s3v.y);
        l0 += p0; l1 += p1; l2 += p2; l3 += p3;
        pw[0 * 72 + lane] = to_bf16(p0);
        pw[1 * 72 + lane] = to_bf16(p1);
        pw[2 * 72 + lane] = to_bf16(p2);
        pw[3 * 72 + lane] = to_bf16(p3);
        LDS_WAIT();    // writes visible to this wave's reads

        // B-frags (p), shared across j-tiles
        const bf16x8 b0 = *(const bf16x8*)(pw + m * 72 + q * 8);
        const bf16x8 b1 = *(const bf16x8*)(pw + m * 72 + q * 8 + 32);
        #pragma unroll
        for (int tt = 0; tt < 4; ++tt) {
            const bf16x8 a0 = *(const bf16x8*)(uw + (16 * tt + m) * 72 + q * 8);
            const bf16x8 a1 = *(const bf16x8*)(uw + (16 * tt + m) * 72 + q * 8 + 32);
            acc[tt] = __builtin_amdgcn_mfma_f32_16x16x32_bf16(a0, b0, acc[tt], 0, 0, 0);
            acc[tt] = __builtin_amdgcn_mfma_f32_16x16x32_bf16(a1, b1, acc[tt], 0, 0, 0);
        }
        LDS_WAIT();    // reads done before next iteration's writes (WAR)
    }

    // l: lane-local partials -> wave reduce
    for (int mm = 1; mm < 64; mm <<= 1) {
        l0 += __shfl_xor(l0, mm);
        l1 += __shfl_xor(l1, mm);
        l2 += __shfl_xor(l2, mm);
        l3 += __shfl_xor(l3, mm);
    }

    // ---- epilogue: transpose D via LDS -> coalesced atomics ----
    float* scr = (float*)uw;   // reuse u region (>= 264 floats available)
    if (m < 4) {
        #pragma unroll
        for (int tt = 0; tt < 4; ++tt)
            #pragma unroll
            for (int reg = 0; reg < 4; ++reg)
                scr[m * 66 + 16 * tt + 4 * q + reg] = acc[tt][reg];
    }
    LDS_WAIT();
    float Th[4];
    #pragma unroll
    for (int h = 0; h < 4; ++h) Th[h] = scr[h * 66 + lane];

    float* accS = accb + (blockIdx.x & (NSLOT - 1)) * SLOTSTRIDE;
    if (lane == 0) {
        atomicAdd(accS + 0, l0);
        atomicAdd(accS + 1, l1);
        atomicAdd(accS + 2, l2);
        atomicAdd(accS + 3, l3);
    }
    atomicAdd(accS + 4 + 0 * 64 + lane, Th[0]);
    atomicAdd(accS + 4 + 1 * 64 + lane, Th[1]);
    atomicAdd(accS + 4 + 2 * 64 + lane, Th[2]);
    atomicAdd(accS + 4 + 3 * 64 + lane, Th[3]);

    // ---- done-counter: last block runs the finish inline ----
    // __syncthreads drains vmcnt(0) -> all this block's atomics complete.
    __syncthreads();
    if (t == 0) {
        __threadfence();
        const unsigned int prev =
            __hip_atomic_fetch_add(cnt, 1u, __ATOMIC_ACQ_REL, __HIP_MEMORY_SCOPE_AGENT);
        lastFlag = (prev == (unsigned int)(K1_BLOCKS - 1));
    }
    __syncthreads();
    if (!lastFlag) return;

    // inline finish (128 threads). LDS reuse: lds[0] region as floats.
    float* red = (float*)&lds[0][0];   // 260 used
    float* sbv = red + 264;            // 256
    float* plv = red + 520;            // 64

    for (int i = t; i < 260; i += K1_THREADS) {
        float a = 0.0f;
        #pragma unroll
        for (int s = 0; s < NSLOT; ++s)
            a += agent_load(accb + s * SLOTSTRIDE + i);
        red[i] = a;
    }
    __syncthreads();

    // S-bar_h[j] = W2[j][:] . (NLN2 * T'_h / l_h) + b2[j]
    for (int idx = t; idx < 256; idx += K1_THREADS) {
        const int h = idx >> 6, j = idx & 63;
        const float inv = NLN2 / red[h];
        float a = 0.0f;
        #pragma unroll 8
        for (int k = 0; k < 64; ++k) a += W2[j * 64 + k] * red[4 + h * 64 + k];
        sbv[idx] = fmaf(inv, a, b2[j]);
    }
    __syncthreads();

    if (t < 64) {
        const int h = t >> 4;
        float a = ipb[128 + t];
        #pragma unroll 8
        for (int d = 0; d < 64; ++d) a += ipw[(128 + t) * 64 + d] * sbv[h * 64 + d];
        plv[t] = a;
    }
    __syncthreads();

    if (t < 64) {
        float a = opb[t];
        #pragma unroll 8
        for (int p = 0; p < 64; ++p) a += opw[t * 64 + p] * plv[p];
        out[t] = a;
    }
}

// ---------------------------------------------------------------------------
extern "C" void kernel_launch(void* const* d_in, const int* in_sizes, int n_in,
                              void* d_out, int out_size, void* d_ws, size_t ws_size,
                              hipStream_t stream)
{
    const float* rr  = (const float*)d_in[0];   // rho_real
    const float* ri  = (const float*)d_in[1];   // rho_imag
    // d_in[2..5]: l_A, l_B, Z_A, Z_B — unused by the reference
    const float* W1  = (const float*)d_in[6];
    const float* b1  = (const float*)d_in[7];
    const float* W2  = (const float*)d_in[8];
    const float* b2  = (const float*)d_in[9];
    const float* qy  = (const float*)d_in[10];
    const float* ipw = (const float*)d_in[11];
    const float* ipb = (const float*)d_in[12];
    const float* opw = (const float*)d_in[13];
    const float* opb = (const float*)d_in[14];
    float* ws  = (float*)d_ws;
    float* out = (float*)d_out;

    setup_kernel<<<64, 64, 0, stream>>>(W1, b1, W2, b2, qy, ipw, ipb, ws);
    main_kernel<<<K1_BLOCKS, K1_THREADS, 0, stream>>>(
        rr, ri,
        (const float4*)(ws + WS_PK),
        ws + WS_D, ws + WS_ACC,
        (unsigned int*)(ws + WS_CNT),
        W2, b2, ipw, ipb, opw, opb, out);
}

// Round 3
// 121.731 us; speedup vs baseline: 1.4346x; 1.4346x over previous
//
#include <hip/hip_runtime.h>

// ---------------------------------------------------------------------------
// UniversalBlockEncoder: algebraically folded attention pooling.
//
//   u_i = silu(W1 x_i + b1)                 (the only per-point nonlinearity)
//   s_h(i) = g_h . u_i + d_h    with g_h = W2^T (scale Wk_h^T q_h)
//   p = exp(s)  (scores O(3), f32-safe without max-subtraction)
//   T_h = sum_i p_h(i) u_i ,  l_h = sum_i p_h(i)
//   out = Wo ( Wv ( W2 (T/l) + b2 ) + bv ) + bo
//
// R10: revert R9's fused finish (its ACQ_REL fence + threadfence per block
//      invalidated K$/L1/L2 for co-resident blocks -> s_load storms, main
//      40->93us). Back to R8's 3-kernel structure. New: atomic-pressure cut
//      ~8x: (a) both waves of a block combine T/l partials in LDS; only
//      wave 0 issues atomics (1.05M -> 532K RMWs); (b) NSLOT 16 -> 64
//      (per-address contention 128 -> 32 RMWs, 4x more cache lines).
//      Phase 1 (packed f32) + phase 2 (MFMA) byte-identical to R8.
// ---------------------------------------------------------------------------

#define LOG2E 1.44269504088896340736f
#define NLN2  (-0.69314718055994530942f)

#if __has_builtin(__builtin_amdgcn_exp2f)
#define EXP2(x) __builtin_amdgcn_exp2f(x)
#else
#define EXP2(x) exp2f(x)
#endif
#if __has_builtin(__builtin_amdgcn_rcpf)
#define RCP(x) __builtin_amdgcn_rcpf(x)
#else
#define RCP(x) (1.0f / (x))
#endif

// LDS-only ordering within a wave (each wave touches only its own region;
// wave lockstep => lgkmcnt(0) is a sufficient producer-consumer barrier).
#define LDS_WAIT() asm volatile("s_waitcnt lgkmcnt(0)" ::: "memory")

typedef __attribute__((ext_vector_type(8))) __bf16 bf16x8;
typedef __attribute__((ext_vector_type(4))) float  f32x4;
typedef __attribute__((ext_vector_type(2))) float  f32x2;

__device__ __forceinline__ f32x2 fma2(f32x2 a, f32x2 b, f32x2 c) {
#if __has_builtin(__builtin_elementwise_fma)
    return __builtin_elementwise_fma(a, b, c);
#else
    return (f32x2){fmaf(a.x, b.x, c.x), fmaf(a.y, b.y, c.y)};
#endif
}

// workspace float offsets
#define WS_PK   0      // 32 pairs x 16 floats (pair-SoA constants)
#define WS_D    512    // 4           : log2e * d_h
#define WS_ACC  768    // NSLOT x SLOTSTRIDE: [0..3]=l_h, [4+h*64+j]=T'_h[j]
#define NSLOT      64
#define SLOTSTRIDE 272

#define NPTS       (1024 * 1024)
#define K1_BLOCKS  2048
#define K1_THREADS 128
#define WAVES_TOTAL (K1_BLOCKS * 2)                   // 4096
#define GROUPS_PER_WAVE ((NPTS / 64) / WAVES_TOTAL)   // 4

// per-wave LDS region (shorts): p[4 x 72] + u[64 x 72]
#define PW_SHORTS  288
#define UW_SHORTS  (64 * 72)
#define WAVE_SHORTS (PW_SHORTS + UW_SHORTS)  // 4896 shorts (9792 B)

__device__ __forceinline__ unsigned short to_bf16(float x) {
    return (unsigned short)((__float_as_uint(x) + 0x8000u) >> 16);
}

// ---------------------------------------------------------------------------
// Setup: 64 blocks x 64 threads. Every block redundantly computes q and a
// (coalesced); block j computes g[j][h] lane-per-d + shuffle reduce. All
// blocks cooperatively zero the accumulator slots.
__global__ void setup_kernel(const float* __restrict__ W1, const float* __restrict__ b1,
                             const float* __restrict__ W2, const float* __restrict__ b2,
                             const float* __restrict__ query,
                             const float* __restrict__ ipw, const float* __restrict__ ipb,
                             float* __restrict__ ws)
{
    __shared__ float qv[64], qs[64], as4[4][64];
    const int t = threadIdx.x;
    const int b = blockIdx.x;     // = output j

    for (int i = b * 64 + t; i < NSLOT * SLOTSTRIDE; i += 64 * 64)
        ws[WS_ACC + i] = 0.0f;

    qv[t] = query[t];
    __syncthreads();

    {
        float a = ipb[t];
        #pragma unroll
        for (int k = 0; k < 64; ++k) a = fmaf(ipw[t * 64 + k], qv[k], a);
        qs[t] = a;
    }
    __syncthreads();

    #pragma unroll
    for (int h = 0; h < 4; ++h) {
        float a = 0.0f;
        #pragma unroll
        for (int m = 0; m < 16; ++m)
            a = fmaf(ipw[(64 + h * 16 + m) * 64 + t], qs[h * 16 + m], a);
        as4[h][t] = 0.25f * a;
    }
    __syncthreads();

    const float w2 = W2[t * 64 + b];
    float g[4];
    #pragma unroll
    for (int h = 0; h < 4; ++h) {
        float v = as4[h][t] * w2;
        for (int m = 1; m < 64; m <<= 1) v += __shfl_xor(v, m);
        g[h] = v;
    }
    if (t == 0) {
        const int base = 16 * (b >> 1);
        const int sub  = b & 1;
        ws[WS_PK + base + 0  + sub] = -LOG2E * W1[2 * b];      // cx
        ws[WS_PK + base + 2  + sub] = -LOG2E * W1[2 * b + 1];  // cy
        ws[WS_PK + base + 4  + sub] = -LOG2E * b1[b];          // cz
        ws[WS_PK + base + 6  + sub] = 0.0f;                    // pad
        ws[WS_PK + base + 8  + sub] = -g[0];                   // -g: LOG2E*NLN2 fold
        ws[WS_PK + base + 10 + sub] = -g[1];
        ws[WS_PK + base + 12 + sub] = -g[2];
        ws[WS_PK + base + 14 + sub] = -g[3];
    }
    if (b == 0 && t < 4) {
        float d = 0.0f;
        #pragma unroll
        for (int c = 0; c < 64; ++c) d += as4[t][c] * b2[c];
        float qb = 0.0f;
        #pragma unroll
        for (int m = 0; m < 16; ++m) qb += qs[t * 16 + m] * ipb[64 + t * 16 + m];
        ws[WS_D + t] = LOG2E * (d + 0.25f * qb);
    }
}

// ---------------------------------------------------------------------------
// Main: 2 independent waves/block (own LDS regions; pure-lgkm waits).
// Phase 1 (lane = point): hidden units in PAIRS via packed f32 math.
// Phase 2: 8x mfma_f32_16x16x32_bf16 per group:
//   D[j-tile(16) x h] += A(u)[m=j][k=pt] * B(p)[k=pt][n=h]
// (B rows n>=4 garbage -> contaminates only D cols >=4, never read.)
// Epilogue: per-wave transpose D via LDS; block-combine across the two
// waves (one __syncthreads); wave 0 issues the (coalesced) atomics.
__global__ __launch_bounds__(K1_THREADS) void main_kernel(
        const float* __restrict__ rr, const float* __restrict__ ri,
        const float4* __restrict__ pk4,
        const float* __restrict__ dvec, float* __restrict__ accb)
{
    __shared__ __align__(16) unsigned short lds[2][WAVE_SHORTS];

    const int t    = threadIdx.x;
    const int lane = t & 63;
    const int w    = t >> 6;
    const int m    = lane & 15;
    const int q    = lane >> 4;

    unsigned short* pw = lds[w];               // p: [h][pt], stride 72
    unsigned short* uw = lds[w] + PW_SHORTS;   // u: [j][pt], stride 72

    const float d0 = dvec[0], d1 = dvec[1], d2 = dvec[2], d3 = dvec[3];

    const int gwave = blockIdx.x * 2 + w;
    float l0 = 0, l1 = 0, l2 = 0, l3 = 0;
    f32x4 acc[4];
    #pragma unroll
    for (int i = 0; i < 4; ++i) acc[i] = (f32x4){0.f, 0.f, 0.f, 0.f};

    // hoist ALL global loads to kernel entry
    float rv[GROUPS_PER_WAVE], iv[GROUPS_PER_WAVE];
    #pragma unroll
    for (int it = 0; it < GROUPS_PER_WAVE; ++it) {
        const int idx = (gwave + it * WAVES_TOTAL) * 64 + lane;
        rv[it] = rr[idx];
        iv[it] = ri[idx];
    }

    for (int it = 0; it < GROUPS_PER_WAVE; ++it) {
        const f32x2 r2 = {rv[it], rv[it]};
        const f32x2 i2 = {iv[it], iv[it]};

        // packed score partials; halves summed after the loop
        f32x2 s0v = {d0, 0.f}, s1v = {d1, 0.f}, s2v = {d2, 0.f}, s3v = {d3, 0.f};

        #pragma unroll 8
        for (int jp = 0; jp < 32; ++jp) {
            const float4 A  = pk4[4 * jp + 0];   // {cx0,cx1,cy0,cy1} wave-uniform
            const float4 B  = pk4[4 * jp + 1];   // {cz0,cz1, 0, 0 }
            const float4 C  = pk4[4 * jp + 2];   // {g00,g01,g10,g11}
            const float4 Dv = pk4[4 * jp + 3];   // {g20,g21,g30,g31}

            const f32x2 cx = {A.x, A.y};
            const f32x2 cy = {A.z, A.w};
            const f32x2 cz = {B.x, B.y};

            const f32x2 zn = fma2(cx, r2, fma2(cy, i2, cz));     // -log2e * z
            const f32x2 e  = {EXP2(zn.x), EXP2(zn.y)};           // exp(-z)
            const f32x2 op = e + (f32x2){1.f, 1.f};
            const f32x2 rc = {RCP(op.x), RCP(op.y)};             // sigmoid(z)
            const f32x2 ub = zn * rc;            // = u / NLN2  (fold)

            s0v = fma2((f32x2){C.x,  C.y},  ub, s0v);
            s1v = fma2((f32x2){C.z,  C.w},  ub, s1v);
            s2v = fma2((f32x2){Dv.x, Dv.y}, ub, s2v);
            s3v = fma2((f32x2){Dv.z, Dv.w}, ub, s3v);

            uw[(2 * jp)     * 72 + lane] = to_bf16(ub.x);
            uw[(2 * jp + 1) * 72 + lane] = to_bf16(ub.y);
        }
        const float p0 = EXP2(s0v.x + s0v.y), p1 = EXP2(s1v.x + s1v.y);
        const float p2 = EXP2(s2v.x + s2v.y), p3 = EXP2(s3v.x + s3v.y);
        l0 += p0; l1 += p1; l2 += p2; l3 += p3;
        pw[0 * 72 + lane] = to_bf16(p0);
        pw[1 * 72 + lane] = to_bf16(p1);
        pw[2 * 72 + lane] = to_bf16(p2);
        pw[3 * 72 + lane] = to_bf16(p3);
        LDS_WAIT();    // writes visible to this wave's reads

        // B-frags (p), shared across j-tiles
        const bf16x8 b0 = *(const bf16x8*)(pw + m * 72 + q * 8);
        const bf16x8 b1 = *(const bf16x8*)(pw + m * 72 + q * 8 + 32);
        #pragma unroll
        for (int tt = 0; tt < 4; ++tt) {
            const bf16x8 a0 = *(const bf16x8*)(uw + (16 * tt + m) * 72 + q * 8);
            const bf16x8 a1 = *(const bf16x8*)(uw + (16 * tt + m) * 72 + q * 8 + 32);
            acc[tt] = __builtin_amdgcn_mfma_f32_16x16x32_bf16(a0, b0, acc[tt], 0, 0, 0);
            acc[tt] = __builtin_amdgcn_mfma_f32_16x16x32_bf16(a1, b1, acc[tt], 0, 0, 0);
        }
        LDS_WAIT();    // reads done before next iteration's writes (WAR)
    }

    // l: lane-local partials -> wave reduce
    for (int mm = 1; mm < 64; mm <<= 1) {
        l0 += __shfl_xor(l0, mm);
        l1 += __shfl_xor(l1, mm);
        l2 += __shfl_xor(l2, mm);
        l3 += __shfl_xor(l3, mm);
    }

    // ---- epilogue: per-wave transpose D via LDS, then block-combine ----
    // D: row = q*4 + reg = j_local(16tt..), col = m = h (cols 4..15 garbage)
    // scr[h][j], stride 66: writes <=2-way banks, reads 2-way (both free).
    float* scr = (float*)uw;   // own wave's u region (>= 268 floats available)
    if (m < 4) {
        #pragma unroll
        for (int tt = 0; tt < 4; ++tt)
            #pragma unroll
            for (int reg = 0; reg < 4; ++reg)
                scr[m * 66 + 16 * tt + 4 * q + reg] = acc[tt][reg];
    }
    // wave 1 publishes its wave-reduced l values alongside its scr
    if (w == 1 && lane == 0) {
        scr[4 * 66 + 0] = l0;
        scr[4 * 66 + 1] = l1;
        scr[4 * 66 + 2] = l2;
        scr[4 * 66 + 3] = l3;
    }
    __syncthreads();   // wave 1's scr + l visible to wave 0

    if (w == 0) {
        const float* scr1 = (const float*)(lds[1] + PW_SHORTS);
        float Th[4];
        #pragma unroll
        for (int h = 0; h < 4; ++h)
            Th[h] = scr[h * 66 + lane] + scr1[h * 66 + lane];

        float* accS = accb + (blockIdx.x & (NSLOT - 1)) * SLOTSTRIDE;
        if (lane == 0) {
            atomicAdd(accS + 0, l0 + scr1[4 * 66 + 0]);
            atomicAdd(accS + 1, l1 + scr1[4 * 66 + 1]);
            atomicAdd(accS + 2, l2 + scr1[4 * 66 + 2]);
            atomicAdd(accS + 3, l3 + scr1[4 * 66 + 3]);
        }
        atomicAdd(accS + 4 + 0 * 64 + lane, Th[0]);
        atomicAdd(accS + 4 + 1 * 64 + lane, Th[1]);
        atomicAdd(accS + 4 + 2 * 64 + lane, Th[2]);
        atomicAdd(accS + 4 + 3 * 64 + lane, Th[3]);
    }
}

// ---------------------------------------------------------------------------
__global__ void finish_kernel(const float* __restrict__ W2, const float* __restrict__ b2,
                              const float* __restrict__ ipw, const float* __restrict__ ipb,
                              const float* __restrict__ opw, const float* __restrict__ opb,
                              const float* __restrict__ ws, float* __restrict__ out)
{
    __shared__ float red[260];   // [0..3]=l, [4+h*64+k]=T'
    __shared__ float sb[256];    // S-bar per (h, j)
    __shared__ float pl[64];     // pooled
    const int t = threadIdx.x;

    {
        float a = 0.0f;
        for (int s = 0; s < NSLOT; ++s) a += ws[WS_ACC + s * SLOTSTRIDE + t];
        red[t] = a;
        if (t < 4) {
            float a2 = 0.0f;
            for (int s = 0; s < NSLOT; ++s) a2 += ws[WS_ACC + s * SLOTSTRIDE + 256 + t];
            red[256 + t] = a2;
        }
    }
    __syncthreads();

    // S-bar_h[j] = W2[j][:] . (NLN2 * T'_h / l_h) + b2[j]
    {
        const int h = t >> 6, j = t & 63;
        const float inv = NLN2 / red[h];
        float a = 0.0f;
        #pragma unroll
        for (int k = 0; k < 64; ++k) a += W2[j * 64 + k] * red[4 + h * 64 + k];
        sb[t] = fmaf(inv, a, b2[j]);
    }
    __syncthreads();

    if (t < 64) {
        const int h = t >> 4;
        float a = ipb[128 + t];
        #pragma unroll
        for (int d = 0; d < 64; ++d) a += ipw[(128 + t) * 64 + d] * sb[h * 64 + d];
        pl[t] = a;
    }
    __syncthreads();

    if (t < 64) {
        float a = opb[t];
        #pragma unroll
        for (int p = 0; p < 64; ++p) a += opw[t * 64 + p] * pl[p];
        out[t] = a;
    }
}

// ---------------------------------------------------------------------------
extern "C" void kernel_launch(void* const* d_in, const int* in_sizes, int n_in,
                              void* d_out, int out_size, void* d_ws, size_t ws_size,
                              hipStream_t stream)
{
    const float* rr  = (const float*)d_in[0];   // rho_real
    const float* ri  = (const float*)d_in[1];   // rho_imag
    // d_in[2..5]: l_A, l_B, Z_A, Z_B — unused by the reference
    const float* W1  = (const float*)d_in[6];
    const float* b1  = (const float*)d_in[7];
    const float* W2  = (const float*)d_in[8];
    const float* b2  = (const float*)d_in[9];
    const float* qy  = (const float*)d_in[10];
    const float* ipw = (const float*)d_in[11];
    const float* ipb = (const float*)d_in[12];
    const float* opw = (const float*)d_in[13];
    const float* opb = (const float*)d_in[14];
    float* ws  = (float*)d_ws;
    float* out = (float*)d_out;

    setup_kernel<<<64, 64, 0, stream>>>(W1, b1, W2, b2, qy, ipw, ipb, ws);
    main_kernel<<<K1_BLOCKS, K1_THREADS, 0, stream>>>(
        rr, ri,
        (const float4*)(ws + WS_PK),
        ws + WS_D, ws + WS_ACC);
    finish_kernel<<<1, 256, 0, stream>>>(W2, b2, ipw, ipb, opw, opb, ws, out);
}